// Round 14
// baseline (160.374 us; speedup 1.0000x reference)
//
#include <hip/hip_runtime.h>
#include <math.h>

#define B_ 32
#define D_ 16
#define T_ 1024
#define P_ 64
#define L_ 32
#define KB 524288.0f       // 2^19 bias: prefmin(e) = KB - prefmax(KB - e)

typedef short short8 __attribute__((ext_vector_type(8)));
typedef float f32x4 __attribute__((ext_vector_type(4)));
typedef unsigned short ushort_t;

// ---- DPP helpers -----------------------------------------------------------
template<int CTRL, int ROW_MASK, bool BC>
__device__ __forceinline__ float dpp_mov(float old_, float src) {
  int o = __builtin_bit_cast(int, old_);
  int s = __builtin_bit_cast(int, src);
  int r = __builtin_amdgcn_update_dpp(o, s, CTRL, ROW_MASK, 0xf, BC);
  return __builtin_bit_cast(float, r);
}

// Inclusive prefix-MAX over each 32-lane half, inputs >= 0 (0-fill identity).
__device__ __forceinline__ float scan_max32(float v) {
  v = fmaxf(v, dpp_mov<0x111, 0xf, true>(0.f, v));   // row_shr:1
  v = fmaxf(v, dpp_mov<0x112, 0xf, true>(0.f, v));   // row_shr:2
  v = fmaxf(v, dpp_mov<0x114, 0xf, true>(0.f, v));   // row_shr:4
  v = fmaxf(v, dpp_mov<0x118, 0xf, true>(0.f, v));   // row_shr:8
  v = fmaxf(v, dpp_mov<0x142, 0xa, false>(0.f, v));  // row_bcast15 -> rows 1,3
  return v;
}

__device__ __forceinline__ ushort_t f2bf(float f) {   // fp32 -> bf16 RNE
  unsigned u = __builtin_bit_cast(unsigned, f);
  return (ushort_t)((u + 0x7FFFu + ((u >> 16) & 1u)) >> 16);
}
__device__ __forceinline__ float bf2f(ushort_t h) {
  unsigned u = ((unsigned)h) << 16;
  return __builtin_bit_cast(float, u);
}

// ---- fused prep ------------------------------------------------------------
// xA[b][t][32 bf16]: [0..15]=x, [16..17]=1, [18..19]=x2hi/lo, [20..31]=0
// pB[p][iblk][lane][8 bf16] holds PREFIX-ACCUMULATED pattern operands so the
// MFMA emits S[i,j] = sum_{k<=i} c[k,j] directly:
//   k<16:  -2 * sum_{m<=i} patt[d=k][m]
//   k=16:  P2hi, k=17: P2lo   (P2 = sum_{m<=i} |patt[:,m]|^2, pairs with 1,1)
//   k=18:  (i+1), k=19: (i+1) (pairs with x2hi,x2lo; exact in bf16, <=32)
//   k>=20: 0
__global__ void prep_all(const float* __restrict__ x,
                         const float* __restrict__ patts,
                         ushort_t* __restrict__ xA,
                         ushort_t* __restrict__ pB) {
  int gid = blockIdx.x * blockDim.x + threadIdx.x;
  if (gid < B_ * T_) {
    int b = gid >> 10, t = gid & 1023;
    float x2 = 0.f;
    ushort_t o[32];
#pragma unroll
    for (int d = 0; d < 16; ++d) {
      float v = x[((b * 16 + d) << 10) + t];   // coalesced over t
      x2 = fmaf(v, v, x2);
      o[d] = f2bf(v);
    }
    o[16] = 0x3F80; o[17] = 0x3F80;            // bf16(1.0)
    ushort_t hi = f2bf(x2);
    o[18] = hi;
    o[19] = f2bf(x2 - bf2f(hi));               // hi/lo split
#pragma unroll
    for (int d = 20; d < 32; ++d) o[d] = 0;
    uint4* dst = (uint4*)(xA + (size_t)gid * 32);
#pragma unroll
    for (int q = 0; q < 4; ++q) {
      const ushort_t* s = o + q * 8;
      uint4 u;
      u.x = (unsigned)s[0] | ((unsigned)s[1] << 16);
      u.y = (unsigned)s[2] | ((unsigned)s[3] << 16);
      u.z = (unsigned)s[4] | ((unsigned)s[5] << 16);
      u.w = (unsigned)s[6] | ((unsigned)s[7] << 16);
      dst[q] = u;
    }
  } else {
    int g2 = gid - B_ * T_;
    if (g2 >= P_ * 2 * 64) return;
    int lane = g2 & 63, iblk = (g2 >> 6) & 1, p = g2 >> 7;
    int n = lane & 15, q = lane >> 4;
    int i = iblk * 16 + n;
    ushort_t o[8];
    if (q < 2) {
#pragma unroll
      for (int e = 0; e < 8; ++e) {
        int d = q * 8 + e;
        float acc = 0.f;
        for (int m = 0; m <= i; ++m)
          acc += patts[((p * 16 + d) << 5) + m];
        o[e] = f2bf(-2.f * acc);
      }
    } else if (q == 2) {
      float P2 = 0.f;
      for (int m = 0; m <= i; ++m) {
#pragma unroll
        for (int d = 0; d < 16; ++d) {
          float t = patts[((p * 16 + d) << 5) + m];
          P2 = fmaf(t, t, P2);
        }
      }
      ushort_t hi = f2bf(P2);
      o[0] = hi; o[1] = f2bf(P2 - bf2f(hi));
      o[2] = f2bf((float)(i + 1)); o[3] = o[2];
      o[4] = o[5] = o[6] = o[7] = 0;
    } else {
#pragma unroll
      for (int e = 0; e < 8; ++e) o[e] = 0;
    }
    uint4 u;
    u.x = (unsigned)o[0] | ((unsigned)o[1] << 16);
    u.y = (unsigned)o[2] | ((unsigned)o[3] << 16);
    u.z = (unsigned)o[4] | ((unsigned)o[5] << 16);
    u.w = (unsigned)o[6] | ((unsigned)o[7] << 16);
    ((uint4*)pB)[g2] = u;
  }
}

// ---- main kernel -----------------------------------------------------------
// 768 blocks x 256 thr = 3 blocks/CU. Wave = 2 patterns. Per 16-col tile:
// 1 A-frag global load + 4 MFMAs -> complete S tile (prefix-B operands) in
// per-wave LDS. DP per column (no sum-scan left):
//   Sx = excl-prefix S = shr1_0(S);  e = w*min(D, shr1(D)) - Sx
//   u  = KB + Sx - w*mn  (>=0)   [R13 bug was KB - Sx: sign of Sx]
//   Dnew = S + prefmin(e) = (S+KB) - prefmax(u)
// Init column of each chunk: Dnew = S (cumsum). Chunks: W=256 warm-up,
// every block exactly 32 tiles, work 1.5x, 3 waves/SIMD for stall overlap.
__global__ __launch_bounds__(256, 3) void dtw_kernel(
    const ushort_t* __restrict__ xA,    // [B][T][32 bf16]
    const ushort_t* __restrict__ pBg,   // [P][2][64][8 bf16]
    const float* __restrict__ wp,
    float* __restrict__ out)            // [B][P][T]
{
  __shared__ float lds[4 * 2560];   // 4 waves * 2 buf * 2 pat * (32*20) fl

  const int tid = threadIdx.x;
  const int l   = tid & 63;
  const int wid = tid >> 6;
  const int li  = l & 31;
  const int g   = l >> 5;
  const int q4  = l >> 4;
  const unsigned bx = blockIdx.x;
  const int ch   = bx % 3u;               // chunk: tiles [16ch, 16ch+32)
  const int rest = bx / 3u;
  const int b     = rest >> 3;
  const int pbase = (rest & 7) << 3;
  const int pA  = pbase + (wid << 1);
  const float w = wp[0];
  const bool l0c = (li == 0), l31 = (li == 31);

  const int t0    = ch << 4;              // 0 / 16 / 32
  const int warmT = ch ? 16 : 0;          // local tiles < warmT: no store

  // B fragments (loop-invariant MFMA operands -> register-resident)
  const short8* pBs = (const short8*)pBg;
  short8 B00 = pBs[((pA    ) * 2 + 0) * 64 + l];
  short8 B01 = pBs[((pA    ) * 2 + 1) * 64 + l];
  short8 B10 = pBs[((pA + 1) * 2 + 0) * 64 + l];
  short8 B11 = pBs[((pA + 1) * 2 + 1) * 64 + l];

  const short8* xAs = (const short8*)xA + ((size_t)b << 12);

  short8 Aa;
  auto loadA = [&](int t) {   // t local; global tile = t0 + t
    Aa = xAs[((((t0 + t) << 4) + (l & 15)) << 2) + q4];
  };

  float* ldsW = lds + wid * 2560 + (l & 15) * 20 + q4 * 4;
  const float* ldsR = lds + wid * 2560 + g * 640 + li * 20;

  auto fill = [&](int bufsel) {
    f32x4 z = {0.f, 0.f, 0.f, 0.f};
    float* wb = ldsW + bufsel * 1280;
    f32x4 d0 = __builtin_amdgcn_mfma_f32_16x16x32_bf16(Aa, B00, z, 0, 0, 0);
    f32x4 d1 = __builtin_amdgcn_mfma_f32_16x16x32_bf16(Aa, B01, z, 0, 0, 0);
    f32x4 d2 = __builtin_amdgcn_mfma_f32_16x16x32_bf16(Aa, B10, z, 0, 0, 0);
    f32x4 d3 = __builtin_amdgcn_mfma_f32_16x16x32_bf16(Aa, B11, z, 0, 0, 0);
    *(f32x4*)(wb + 0)   = d0;      // pat0, i 0..15   ([i][j] stride 20)
    *(f32x4*)(wb + 320) = d1;      // pat0, i 16..31
    *(f32x4*)(wb + 640) = d2;      // pat1, i 0..15
    *(f32x4*)(wb + 960) = d3;      // pat1, i 16..31
  };

  float* orow = out + (((size_t)(b * P_ + pA + g)) << 10) + (t0 << 4);
  float dcur = 0.f;

  // core column update from S (no sum-scan): ~15 issue slots
  auto col = [&](float S) -> float {
    float Sx = dpp_mov<0x138, 0xf, true>(0.f, S);     // excl prefix: shr1_0
    Sx = l0c ? 0.f : Sx;                              // lane0/32 -> 0
    float t1 = KB + Sx;                               // off critical path (+Sx!)
    float pu = dpp_mov<0x138, 0xf, true>(0.f, dcur);  // D[i-1] from prev col
    pu = l0c ? dcur : pu;
    float mn = fminf(dcur, pu);
    float u  = fmaf(-w, mn, t1);                      // u = KB + Sx - w*mn >= 0
    float Mx = scan_max32(u);
    return (S + KB) - Mx;                             // S + prefmin(e)
  };

  auto DP = [&](int bufsel, bool first, bool store, float* op) {
    const float* rb = ldsR + bufsel * 1280;
    f32x4 q0 = *(const f32x4*)(rb + 0);     // 4 reads up-front: one lgkm
    f32x4 q1 = *(const f32x4*)(rb + 4);     // cluster, staged waits
    f32x4 q2 = *(const f32x4*)(rb + 8);
    f32x4 q3 = *(const f32x4*)(rb + 12);
#pragma unroll
    for (int k4 = 0; k4 < 4; ++k4) {
      f32x4 Sq = (k4 == 0) ? q0 : (k4 == 1) ? q1 : (k4 == 2) ? q2 : q3;
      float sv0, sv1, sv2, sv3;
#pragma unroll
      for (int e = 0; e < 4; ++e) {
        float val = col(Sq[e]);
        if (first && k4 == 0 && e == 0)                 // init col = cumsum
          val = Sq[0];                                  // ... which IS S
        dcur = val;
        if (e == 0) sv0 = val; else if (e == 1) sv1 = val;
        else if (e == 2) sv2 = val; else sv3 = val;
      }
      if (store) {                                      // uniform per tile
        float4 sv;
        sv.x = __builtin_amdgcn_sqrtf(sv0);
        sv.y = __builtin_amdgcn_sqrtf(sv1);
        sv.z = __builtin_amdgcn_sqrtf(sv2);
        sv.w = __builtin_amdgcn_sqrtf(sv3);
        if (l31) *(float4*)(op + k4 * 4) = sv;          // 1 dwordx4 / 4 cols
      }
    }
  };

  loadA(0);
  fill(0);
  loadA(1);
  for (int t = 0; t < 32; ++t) {
    if (t + 1 < 32) fill((t & 1) ^ 1);   // consumes Aa = frag(t+1)
    if (t + 2 < 32) loadA(t + 2);
    DP(t & 1, t == 0, t >= warmT, orow + (t << 4));
  }
}

extern "C" void kernel_launch(void* const* d_in, const int* in_sizes, int n_in,
                              void* d_out, int out_size, void* d_ws, size_t ws_size,
                              hipStream_t stream) {
  const float* x     = (const float*)d_in[0];
  const float* patts = (const float*)d_in[1];
  const float* w     = (const float*)d_in[2];
  float* out = (float*)d_out;

  ushort_t* xA = (ushort_t*)d_ws;                                       // 2 MiB
  ushort_t* pB = (ushort_t*)((char*)d_ws + (size_t)B_ * T_ * 32 * 2);   // 128 KiB

  prep_all<<<(B_ * T_ + P_ * 2 * 64 + 255) / 256, 256, 0, stream>>>(x, patts, xA, pB);
  dtw_kernel<<<B_ * (P_ / 8) * 3, 256, 0, stream>>>(xA, pB, w, out);
}

// Round 15
// 141.394 us; speedup vs baseline: 1.1342x; 1.1342x over previous
//
#include <hip/hip_runtime.h>
#include <math.h>

#define B_ 32
#define D_ 16
#define T_ 1024
#define P_ 64
#define L_ 32
#define KB 524288.0f       // 2^19 bias: prefmin(e) = KB - prefmax(KB - e)

typedef short short8 __attribute__((ext_vector_type(8)));
typedef float f32x4 __attribute__((ext_vector_type(4)));
typedef unsigned short ushort_t;

// ---- DPP helpers -----------------------------------------------------------
template<int CTRL, int ROW_MASK, bool BC>
__device__ __forceinline__ float dpp_mov(float old_, float src) {
  int o = __builtin_bit_cast(int, old_);
  int s = __builtin_bit_cast(int, src);
  int r = __builtin_amdgcn_update_dpp(o, s, CTRL, ROW_MASK, 0xf, BC);
  return __builtin_bit_cast(float, r);
}

// Inclusive prefix-sum over each 32-lane half (0-fill -> fused v_add_f32_dpp).
__device__ __forceinline__ float scan_sum32(float v) {
  v += dpp_mov<0x111, 0xf, true>(0.f, v);   // row_shr:1
  v += dpp_mov<0x112, 0xf, true>(0.f, v);   // row_shr:2
  v += dpp_mov<0x114, 0xf, true>(0.f, v);   // row_shr:4
  v += dpp_mov<0x118, 0xf, true>(0.f, v);   // row_shr:8
  v += dpp_mov<0x142, 0xa, false>(0.f, v);  // row_bcast15 -> rows 1,3
  return v;
}

// Inclusive prefix-MAX over each 32-lane half, inputs >= 0 (0-fill identity).
__device__ __forceinline__ float scan_max32(float v) {
  v = fmaxf(v, dpp_mov<0x111, 0xf, true>(0.f, v));   // row_shr:1
  v = fmaxf(v, dpp_mov<0x112, 0xf, true>(0.f, v));   // row_shr:2
  v = fmaxf(v, dpp_mov<0x114, 0xf, true>(0.f, v));   // row_shr:4
  v = fmaxf(v, dpp_mov<0x118, 0xf, true>(0.f, v));   // row_shr:8
  v = fmaxf(v, dpp_mov<0x142, 0xa, false>(0.f, v));  // row_bcast15 -> rows 1,3
  return v;
}

__device__ __forceinline__ ushort_t f2bf(float f) {   // fp32 -> bf16 RNE
  unsigned u = __builtin_bit_cast(unsigned, f);
  return (ushort_t)((u + 0x7FFFu + ((u >> 16) & 1u)) >> 16);
}
__device__ __forceinline__ float bf2f(ushort_t h) {
  unsigned u = ((unsigned)h) << 16;
  return __builtin_bit_cast(float, u);
}

// ---- prep_x: xA[b][t][32 bf16] --------------------------------------------
// [0..15]=x, [16..17]=1, [18..19]=x2hi/lo, [20..31]=0   (byte-identical to R14)
__global__ void prep_x(const float* __restrict__ x, ushort_t* __restrict__ xA) {
  int gid = blockIdx.x * blockDim.x + threadIdx.x;
  if (gid >= B_ * T_) return;
  int b = gid >> 10, t = gid & 1023;
  float x2 = 0.f;
  ushort_t o[32];
#pragma unroll
  for (int d = 0; d < 16; ++d) {
    float v = x[((b * 16 + d) << 10) + t];   // coalesced over t
    x2 = fmaf(v, v, x2);
    o[d] = f2bf(v);
  }
  o[16] = 0x3F80; o[17] = 0x3F80;            // bf16(1.0)
  ushort_t hi = f2bf(x2);
  o[18] = hi;
  o[19] = f2bf(x2 - bf2f(hi));               // hi/lo split
#pragma unroll
  for (int d = 20; d < 32; ++d) o[d] = 0;
  uint4* dst = (uint4*)(xA + (size_t)gid * 32);
#pragma unroll
  for (int q = 0; q < 4; ++q) {
    const ushort_t* s = o + q * 8;
    uint4 u;
    u.x = (unsigned)s[0] | ((unsigned)s[1] << 16);
    u.y = (unsigned)s[2] | ((unsigned)s[3] << 16);
    u.z = (unsigned)s[4] | ((unsigned)s[5] << 16);
    u.w = (unsigned)s[6] | ((unsigned)s[7] << 16);
    dst[q] = u;
  }
}

// ---- prep_patt: PREFIX-ACCUMULATED B fragments via DPP scans ---------------
// One 64-thread block per pattern p. Lane m holds patt[p][d][m] (coalesced);
// DPP scan_sum32 gives prefix over m in 5 ops (two d's per pass, one per
// half). Transposed through 2.2 KB LDS; output lanes gather 8 values each.
// Replaces R14's serial O(i) loops (up to 512 dependent global reads/lane,
// +30us on the bench).
// pB[p][iblk][lane][8 bf16]: k<16: -2*sum_{m<=i}patt[d=k][m];
// k=16/17: P2hi/lo (P2=sum_{m<=i}|patt[:,m]|^2); k=18/19: (i+1); k>=20: 0.
__global__ __launch_bounds__(64) void prep_patt(const float* __restrict__ patts,
                                                ushort_t* __restrict__ pB) {
  __shared__ float Ls[16 * 33];    // [d][m], stride 33 (conflict-free gathers)
  __shared__ float Lh[64];         // per-half p2 partial sums
  __shared__ float LP2[32];        // prefix of p2 totals

  const int p = blockIdx.x;
  const int l = threadIdx.x;
  const int half = l >> 5;
  const int m = l & 31;

  float p2acc = 0.f;
#pragma unroll
  for (int dd = 0; dd < 16; dd += 2) {
    int d = dd + half;                       // half 0: even d, half 1: odd d
    float v = patts[((p * 16 + d) << 5) + m];
    p2acc = fmaf(v, v, p2acc);
    Ls[d * 33 + m] = scan_sum32(v);          // prefix over m (per half)
  }
  Lh[l] = p2acc;
  __syncthreads();
  {
    float tot = Lh[m] + Lh[32 + m];          // both halves compute (redundant)
    float pref = scan_sum32(tot);
    if (half == 0) LP2[m] = pref;
  }
  __syncthreads();

  // output: 2 iblks x 64 lanes; lane l -> n=l&15, q=l>>4, i=iblk*16+n
  const int n = l & 15, q = l >> 4;
#pragma unroll
  for (int iblk = 0; iblk < 2; ++iblk) {
    const int i = iblk * 16 + n;
    ushort_t o[8];
    if (q < 2) {
#pragma unroll
      for (int e = 0; e < 8; ++e)
        o[e] = f2bf(-2.f * Ls[(q * 8 + e) * 33 + i]);
    } else if (q == 2) {
      float P2 = LP2[i];
      ushort_t hi = f2bf(P2);
      o[0] = hi; o[1] = f2bf(P2 - bf2f(hi));
      o[2] = f2bf((float)(i + 1)); o[3] = o[2];
      o[4] = o[5] = o[6] = o[7] = 0;
    } else {
#pragma unroll
      for (int e = 0; e < 8; ++e) o[e] = 0;
    }
    uint4 u;
    u.x = (unsigned)o[0] | ((unsigned)o[1] << 16);
    u.y = (unsigned)o[2] | ((unsigned)o[3] << 16);
    u.z = (unsigned)o[4] | ((unsigned)o[5] << 16);
    u.w = (unsigned)o[6] | ((unsigned)o[7] << 16);
    ((uint4*)pB)[(p * 2 + iblk) * 64 + l] = u;
  }
}

// ---- main kernel (byte-identical to R14: 85.5us, VALUBusy 82%) -------------
// 768 blocks x 256 thr = 3 blocks/CU. Wave = 2 patterns. Per 16-col tile:
// 1 A-frag global load + 4 MFMAs -> complete S tile (prefix-B operands) in
// per-wave LDS. DP per column (no sum-scan):
//   Sx = excl-prefix S = shr1_0(S);  u = KB + Sx - w*min(D, shr1(D))
//   Dnew = (S+KB) - prefmax(u)
// Init column of each chunk: Dnew = S (cumsum). Chunks: W=256 warm-up,
// every block exactly 32 tiles, work 1.5x, 3 waves/SIMD for stall overlap.
__global__ __launch_bounds__(256, 3) void dtw_kernel(
    const ushort_t* __restrict__ xA,    // [B][T][32 bf16]
    const ushort_t* __restrict__ pBg,   // [P][2][64][8 bf16]
    const float* __restrict__ wp,
    float* __restrict__ out)            // [B][P][T]
{
  __shared__ float lds[4 * 2560];   // 4 waves * 2 buf * 2 pat * (32*20) fl

  const int tid = threadIdx.x;
  const int l   = tid & 63;
  const int wid = tid >> 6;
  const int li  = l & 31;
  const int g   = l >> 5;
  const int q4  = l >> 4;
  const unsigned bx = blockIdx.x;
  const int ch   = bx % 3u;               // chunk: tiles [16ch, 16ch+32)
  const int rest = bx / 3u;
  const int b     = rest >> 3;
  const int pbase = (rest & 7) << 3;
  const int pA  = pbase + (wid << 1);
  const float w = wp[0];
  const bool l0c = (li == 0), l31 = (li == 31);

  const int t0    = ch << 4;              // 0 / 16 / 32
  const int warmT = ch ? 16 : 0;          // local tiles < warmT: no store

  // B fragments (loop-invariant MFMA operands -> register-resident)
  const short8* pBs = (const short8*)pBg;
  short8 B00 = pBs[((pA    ) * 2 + 0) * 64 + l];
  short8 B01 = pBs[((pA    ) * 2 + 1) * 64 + l];
  short8 B10 = pBs[((pA + 1) * 2 + 0) * 64 + l];
  short8 B11 = pBs[((pA + 1) * 2 + 1) * 64 + l];

  const short8* xAs = (const short8*)xA + ((size_t)b << 12);

  short8 Aa;
  auto loadA = [&](int t) {   // t local; global tile = t0 + t
    Aa = xAs[((((t0 + t) << 4) + (l & 15)) << 2) + q4];
  };

  float* ldsW = lds + wid * 2560 + (l & 15) * 20 + q4 * 4;
  const float* ldsR = lds + wid * 2560 + g * 640 + li * 20;

  auto fill = [&](int bufsel) {
    f32x4 z = {0.f, 0.f, 0.f, 0.f};
    float* wb = ldsW + bufsel * 1280;
    f32x4 d0 = __builtin_amdgcn_mfma_f32_16x16x32_bf16(Aa, B00, z, 0, 0, 0);
    f32x4 d1 = __builtin_amdgcn_mfma_f32_16x16x32_bf16(Aa, B01, z, 0, 0, 0);
    f32x4 d2 = __builtin_amdgcn_mfma_f32_16x16x32_bf16(Aa, B10, z, 0, 0, 0);
    f32x4 d3 = __builtin_amdgcn_mfma_f32_16x16x32_bf16(Aa, B11, z, 0, 0, 0);
    *(f32x4*)(wb + 0)   = d0;      // pat0, i 0..15   ([i][j] stride 20)
    *(f32x4*)(wb + 320) = d1;      // pat0, i 16..31
    *(f32x4*)(wb + 640) = d2;      // pat1, i 0..15
    *(f32x4*)(wb + 960) = d3;      // pat1, i 16..31
  };

  float* orow = out + (((size_t)(b * P_ + pA + g)) << 10) + (t0 << 4);
  float dcur = 0.f;

  // core column update from S (no sum-scan): ~15 issue slots
  auto col = [&](float S) -> float {
    float Sx = dpp_mov<0x138, 0xf, true>(0.f, S);     // excl prefix: shr1_0
    Sx = l0c ? 0.f : Sx;                              // lane0/32 -> 0
    float t1 = KB + Sx;                               // off critical path
    float pu = dpp_mov<0x138, 0xf, true>(0.f, dcur);  // D[i-1] from prev col
    pu = l0c ? dcur : pu;
    float mn = fminf(dcur, pu);
    float u  = fmaf(-w, mn, t1);                      // u = KB + Sx - w*mn >= 0
    float Mx = scan_max32(u);
    return (S + KB) - Mx;                             // S + prefmin(e)
  };

  auto DP = [&](int bufsel, bool first, bool store, float* op) {
    const float* rb = ldsR + bufsel * 1280;
    f32x4 q0 = *(const f32x4*)(rb + 0);     // 4 reads up-front: one lgkm
    f32x4 q1 = *(const f32x4*)(rb + 4);     // cluster, staged waits
    f32x4 q2 = *(const f32x4*)(rb + 8);
    f32x4 q3 = *(const f32x4*)(rb + 12);
#pragma unroll
    for (int k4 = 0; k4 < 4; ++k4) {
      f32x4 Sq = (k4 == 0) ? q0 : (k4 == 1) ? q1 : (k4 == 2) ? q2 : q3;
      float sv0, sv1, sv2, sv3;
#pragma unroll
      for (int e = 0; e < 4; ++e) {
        float val = col(Sq[e]);
        if (first && k4 == 0 && e == 0)                 // init col = cumsum
          val = Sq[0];                                  // ... which IS S
        dcur = val;
        if (e == 0) sv0 = val; else if (e == 1) sv1 = val;
        else if (e == 2) sv2 = val; else sv3 = val;
      }
      if (store) {                                      // uniform per tile
        float4 sv;
        sv.x = __builtin_amdgcn_sqrtf(sv0);
        sv.y = __builtin_amdgcn_sqrtf(sv1);
        sv.z = __builtin_amdgcn_sqrtf(sv2);
        sv.w = __builtin_amdgcn_sqrtf(sv3);
        if (l31) *(float4*)(op + k4 * 4) = sv;          // 1 dwordx4 / 4 cols
      }
    }
  };

  loadA(0);
  fill(0);
  loadA(1);
  for (int t = 0; t < 32; ++t) {
    if (t + 1 < 32) fill((t & 1) ^ 1);   // consumes Aa = frag(t+1)
    if (t + 2 < 32) loadA(t + 2);
    DP(t & 1, t == 0, t >= warmT, orow + (t << 4));
  }
}

extern "C" void kernel_launch(void* const* d_in, const int* in_sizes, int n_in,
                              void* d_out, int out_size, void* d_ws, size_t ws_size,
                              hipStream_t stream) {
  const float* x     = (const float*)d_in[0];
  const float* patts = (const float*)d_in[1];
  const float* w     = (const float*)d_in[2];
  float* out = (float*)d_out;

  ushort_t* xA = (ushort_t*)d_ws;                                       // 2 MiB
  ushort_t* pB = (ushort_t*)((char*)d_ws + (size_t)B_ * T_ * 32 * 2);   // 128 KiB

  prep_x<<<(B_ * T_ + 255) / 256, 256, 0, stream>>>(x, xA);
  prep_patt<<<P_, 64, 0, stream>>>(patts, pB);
  dtw_kernel<<<B_ * (P_ / 8) * 3, 256, 0, stream>>>(xA, pB, w, out);
}